// Round 13
// baseline (176.903 us; speedup 1.0000x reference)
//
#include <hip/hip_runtime.h>
#include <math.h>

#define SEQ 2048
#define DIMD 1024
#define NH 16
#define HDIM 64

typedef _Float16 h8 __attribute__((ext_vector_type(8)));
typedef _Float16 h4 __attribute__((ext_vector_type(4)));
typedef __fp16 fp16x2 __attribute__((ext_vector_type(2)));
typedef float f32x4 __attribute__((ext_vector_type(4)));

typedef const __attribute__((address_space(1))) void* gas_t;
typedef __attribute__((address_space(3))) void* las_t;

// element-index swizzle for [*][64] f16 tiles (128B rows): XOR element bits
// 3-5 with (row&7).  Permutes 16B chunks within a row.
__device__ __forceinline__ int SWE(int r, int c) {
  return ((r << 6) + c) ^ ((r & 7) << 3);
}

// ---------------------------------------------------------------------------
// Fused prep: RoPE table (double precision) + f32->f16 converts.
// ---------------------------------------------------------------------------
#define R0 16384           // rope items (x4 idx each)
#define R1 (R0 + 1048576)  // query f32x4
#define R2 (R1 + 524288)   // Wq
#define R3 (R2 + 262144)   // Wk
#define R4 (R3 + 262144)   // Wv
#define R5 (R4 + 262144)   // Wo

__global__ void prep_kernel(const float* __restrict__ query,
                            const float* __restrict__ Wq,
                            const float* __restrict__ Wk,
                            const float* __restrict__ Wv,
                            const float* __restrict__ Wo,
                            _Float16* __restrict__ Ah,
                            _Float16* __restrict__ Wqh,
                            _Float16* __restrict__ Wkh,
                            _Float16* __restrict__ Wvh,
                            _Float16* __restrict__ Woh,
                            float* __restrict__ sintab,
                            float* __restrict__ costab) {
  int i = blockIdx.x * 256 + threadIdx.x;
  if (i < R0) {
#pragma unroll
    for (int j = 0; j < 4; ++j) {
      int idx = i * 4 + j;
      int tp = idx >> 5;
      int fi = idx & 31;
      double inv = pow(10000.0, -(double)(2 * fi) / 64.0);
      double a = (double)tp * inv;
      sintab[idx] = (float)sin(a);
      costab[idx] = (float)cos(a);
    }
    return;
  }
  const float* src;
  _Float16* dst;
  int k;
  if (i < R1) {
    k = i - R0; src = query; dst = Ah;
  } else if (i < R2) {
    k = i - R1; src = Wq; dst = Wqh;
  } else if (i < R3) {
    k = i - R2; src = Wk; dst = Wkh;
  } else if (i < R4) {
    k = i - R3; src = Wv; dst = Wvh;
  } else if (i < R5) {
    k = i - R4; src = Wo; dst = Woh;
  } else {
    return;
  }
  float4 v = ((const float4*)src)[k];
  h4 H;
  H[0] = (_Float16)v.x;
  H[1] = (_Float16)v.y;
  H[2] = (_Float16)v.z;
  H[3] = (_Float16)v.w;
  ((h4*)dst)[k] = H;
}

// ---------------------------------------------------------------------------
// Fused QKV projection GEMM, concat N=4096.  256x256 8-phase template (m201
// port): BK=64, 512 thr = 8 waves (2m x 4n, 128x64 out each), 2-slot LDS
// dbuf 128KB, 4 phases/K-step (quadrant 4mi x 2ni x 2kk = 16 MFMA), one
// half-tile staged per phase, uniform vmcnt(2) once per K-step.  Grid 16x16.
// ---------------------------------------------------------------------------
__global__ __launch_bounds__(512, 2) void qkv_kernel(
    const _Float16* __restrict__ Ah, const _Float16* __restrict__ Wqh,
    const _Float16* __restrict__ Wkh, const _Float16* __restrict__ Wvh,
    const float* __restrict__ bq, const float* __restrict__ bk,
    const float* __restrict__ bv, _Float16* __restrict__ qw,
    _Float16* __restrict__ sg, _Float16* __restrict__ kw,
    _Float16* __restrict__ vtw, const float* __restrict__ sintab,
    const float* __restrict__ costab) {
  __shared__ _Float16 Abuf[2][16384];  // 2 slots x [256][64] swizzled = 64 KB
  __shared__ _Float16 Bbuf[2][16384];  // 64 KB
  const int t = threadIdx.x;
  const int lane = t & 63;
  const int w = t >> 6;       // 0..7
  const int wm = w >> 2;      // 0..1: 128-row half
  const int wn = w & 3;       // 0..3: 64-col slice
  const int fr = lane & 15;
  const int g = lane >> 4;
  const int m0 = blockIdx.y * 256;
  const int n0 = blockIdx.x * 256;
  const int region = (n0 < 2048) ? 0 : (n0 < 3072 ? 1 : 2);
  const _Float16* Wb = region == 0   ? Wqh + (size_t)n0 * DIMD
                       : region == 1 ? Wkh + (size_t)(n0 - 2048) * DIMD
                                     : Wvh + (size_t)(n0 - 3072) * DIMD;

  f32x4 acc[8][4];
#pragma unroll
  for (int i = 0; i < 8; ++i)
#pragma unroll
    for (int j = 0; j < 4; ++j) acc[i][j] = (f32x4){0.f, 0.f, 0.f, 0.f};

  // staging: half = 128 rows x 64 k of one operand; 2 issues/thread.
  // thread t covers chunks t and t+512 (chunk = 16B); row_local = chunk>>3,
  // source chunk pre-swizzled by row&7; LDS dest linear (= SWE layout).
  const int csw = ((t & 7) ^ ((t >> 3) & 7)) << 3;
  const _Float16* gA = Ah + (size_t)(m0 + (t >> 3)) * DIMD + csw;
  const _Float16* gB = Wb + (size_t)(t >> 3) * DIMD + csw;

  // half id hf: 0 = A rows 0-127, 1 = A rows 128-255, 2 = B rows 0-127,
  // 3 = B rows 128-255
  auto stage_half = [&](int kt, int hf, int sl) {
    const int r0 = (hf & 1) * 128;
    if (hf < 2) {
#pragma unroll
      for (int i = 0; i < 2; ++i)
        __builtin_amdgcn_global_load_lds(
            (gas_t)(gA + (size_t)(r0 + i * 64) * DIMD + kt * 64),
            (las_t)&Abuf[sl][(hf & 1) * 8192 + (i * 512 + t) * 8], 16, 0, 0);
    } else {
#pragma unroll
      for (int i = 0; i < 2; ++i)
        __builtin_amdgcn_global_load_lds(
            (gas_t)(gB + (size_t)(r0 + i * 64) * DIMD + kt * 64),
            (las_t)&Bbuf[sl][(hf & 1) * 8192 + (i * 512 + t) * 8], 16, 0, 0);
    }
  };

  // prologue: K-step 0 into slot 0
#pragma unroll
  for (int hf = 0; hf < 4; ++hf) stage_half(0, hf, 0);

  for (int kt = 0; kt < 16; ++kt) {
    const int sl = kt & 1;
#pragma unroll
    for (int q = 0; q < 4; ++q) {
      const int mh = q >> 1, nh = q & 1;
      if (kt + 1 < 16) stage_half(kt + 1, q, sl ^ 1);
      if (q == 0) {
        // uniform wait: all 8 loads of slot sl done; next A0 pair in flight
        if (kt + 1 < 16)
          asm volatile("s_waitcnt vmcnt(2)" ::: "memory");
        else
          asm volatile("s_waitcnt vmcnt(0)" ::: "memory");
        __builtin_amdgcn_sched_barrier(0);
        __builtin_amdgcn_s_barrier();  // slot sl globally complete
      }
      // ds-read this phase's quadrant frags
      h8 av[4][2], bv[2][2];
#pragma unroll
      for (int mi = 0; mi < 4; ++mi)
#pragma unroll
        for (int kk = 0; kk < 2; ++kk)
          av[mi][kk] = *(const h8*)&Abuf[sl][wm * 8192 +
                                            SWE(mh * 64 + mi * 16 + fr,
                                                8 * g + 32 * kk)];
#pragma unroll
      for (int ni = 0; ni < 2; ++ni)
#pragma unroll
        for (int kk = 0; kk < 2; ++kk)
          bv[ni][kk] = *(const h8*)&Bbuf[sl][(wn >> 1) * 8192 +
                                             SWE((wn & 1) * 64 + nh * 32 +
                                                     ni * 16 + fr,
                                                 8 * g + 32 * kk)];
      if (q != 0) __builtin_amdgcn_s_barrier();
      asm volatile("s_waitcnt lgkmcnt(0)" ::: "memory");
      __builtin_amdgcn_sched_barrier(0);
      __builtin_amdgcn_s_setprio(1);
#pragma unroll
      for (int kk = 0; kk < 2; ++kk)
#pragma unroll
        for (int mi = 0; mi < 4; ++mi)
#pragma unroll
          for (int ni = 0; ni < 2; ++ni)
            acc[mh * 4 + mi][nh * 2 + ni] =
                __builtin_amdgcn_mfma_f32_16x16x32_f16(
                    av[mi][kk], bv[ni][kk], acc[mh * 4 + mi][nh * 2 + ni], 0,
                    0, 0);
      __builtin_amdgcn_s_setprio(0);
      __builtin_amdgcn_s_barrier();
    }
  }

  // Epilogue. C/D layout: col = lane&15, row = (lane>>4)*4 + reg.
  // acc[mi] -> row offset (mi>>2)*64 + (mi&3)*16; acc[..][ni] -> col offset
  // (ni>>1)*32 + (ni&1)*16.
#pragma unroll
  for (int mi = 0; mi < 8; ++mi)
#pragma unroll
    for (int ni = 0; ni < 4; ++ni) {
      const int colg = n0 + wn * 64 + (ni >> 1) * 32 + (ni & 1) * 16 + fr;
      const float bsv = region == 0   ? bq[colg]
                        : region == 1 ? bk[colg - 2048]
                                      : bv[colg - 3072];
      const int row0 =
          m0 + wm * 128 + (mi >> 2) * 64 + (mi & 3) * 16 + g * 4;
      if (region == 2) {  // V: vectorized h4 store (4 consecutive s)
        const int vc = colg - 3072;
        const int h = vc >> 6, d = vc & 63;
        const int b = row0 >> 11;
        const int s0 = row0 & (SEQ - 1);
        h4 vv;
#pragma unroll
        for (int r = 0; r < 4; ++r) vv[r] = (_Float16)(acc[mi][ni][r] + bsv);
        *(h4*)&vtw[((size_t)(b * NH + h) * HDIM + d) * SEQ + s0] = vv;
        continue;
      }
#pragma unroll
      for (int r = 0; r < 4; ++r) {
        const int row = row0 + r;
        float v = acc[mi][ni][r] + bsv;
        const int b = row >> 11;
        const int s = row & (SEQ - 1);
        if (region == 0) {
          const int h = colg >> 7;
          const int d = colg & 63;
          if (((colg >> 6) & 1) == 0) {  // q: rope + SCALE
            float vp = __shfl_xor(v, 1);
            const int pi = s * 32 + (d >> 1);
            float sn = sintab[pi], cs = costab[pi];
            float rv = (d & 1) ? (vp * sn + v * cs) : (v * cs - vp * sn);
            rv *= 0.125f;
            qw[((size_t)(b * NH + h) * SEQ + s) * HDIM + d] = (_Float16)rv;
          } else {  // gate: sigmoid -> (B,S,D)
            float gv = 1.0f / (1.0f + __expf(-v));
            sg[((size_t)(b * SEQ + s)) * DIMD + h * HDIM + d] = (_Float16)gv;
          }
        } else {  // region 1: K rope
          const int kc = colg - 2048;
          const int h = kc >> 6, d = kc & 63;
          float vp = __shfl_xor(v, 1);
          const int pi = s * 32 + (d >> 1);
          float sn = sintab[pi], cs = costab[pi];
          float rv = (d & 1) ? (vp * sn + v * cs) : (v * cs - vp * sn);
          kw[((size_t)(b * NH + h) * SEQ + s) * HDIM + d] = (_Float16)rv;
        }
      }
    }
}

// ---------------------------------------------------------------------------
// O-projection GEMM (plain f16): BM=128, BN=64, BK=64, single-buffer (24KB),
// 4 waves (2x2) of 64x32.  Grid (16 n, 32 m).  (r9 known-good form)
// ---------------------------------------------------------------------------
__global__ __launch_bounds__(256) void ogemm_kernel(
    const _Float16* __restrict__ ag, const _Float16* __restrict__ Woh,
    const float* __restrict__ bias, float* __restrict__ out) {
  __shared__ _Float16 Abuf[8192];  // [128][64] swizzled
  __shared__ _Float16 Bbuf[4096];  // [64][64] swizzled
  const int t = threadIdx.x;
  const int lane = t & 63;
  const int w = t >> 6;
  const int wm = w & 1, wn = w >> 1;
  const int fr = lane & 15;
  const int g = lane >> 4;
  const int m0 = blockIdx.y * 128, n0 = blockIdx.x * 64;

  f32x4 acc[4][2];
#pragma unroll
  for (int i = 0; i < 4; ++i)
#pragma unroll
    for (int j = 0; j < 2; ++j) acc[i][j] = (f32x4){0.f, 0.f, 0.f, 0.f};

  const int rsub = t >> 3;
  const int csw = ((t & 7) ^ (rsub & 7)) << 3;
  const _Float16* gA = ag + (size_t)(m0 + rsub) * DIMD + csw;
  const _Float16* gB = Woh + (size_t)(n0 + rsub) * DIMD + csw;

  for (int kt = 0; kt < 16; ++kt) {
#pragma unroll
    for (int i = 0; i < 4; ++i)
      __builtin_amdgcn_global_load_lds(
          (gas_t)(gA + (size_t)i * 32 * DIMD + kt * 64),
          (las_t)&Abuf[i * 2048 + t * 8], 16, 0, 0);
#pragma unroll
    for (int i = 0; i < 2; ++i)
      __builtin_amdgcn_global_load_lds(
          (gas_t)(gB + (size_t)i * 32 * DIMD + kt * 64),
          (las_t)&Bbuf[i * 2048 + t * 8], 16, 0, 0);
    __syncthreads();
#pragma unroll
    for (int s = 0; s < 2; ++s) {
      h8 av[4], bv[2];
#pragma unroll
      for (int mi = 0; mi < 4; ++mi)
        av[mi] = *(const h8*)&Abuf[SWE(wm * 64 + mi * 16 + fr, 8 * g + 32 * s)];
#pragma unroll
      for (int ni = 0; ni < 2; ++ni)
        bv[ni] = *(const h8*)&Bbuf[SWE(wn * 32 + ni * 16 + fr, 8 * g + 32 * s)];
      __builtin_amdgcn_s_setprio(1);
#pragma unroll
      for (int mi = 0; mi < 4; ++mi)
#pragma unroll
        for (int ni = 0; ni < 2; ++ni)
          acc[mi][ni] = __builtin_amdgcn_mfma_f32_16x16x32_f16(
              av[mi], bv[ni], acc[mi][ni], 0, 0, 0);
      __builtin_amdgcn_s_setprio(0);
    }
    __syncthreads();
  }

#pragma unroll
  for (int mi = 0; mi < 4; ++mi)
#pragma unroll
    for (int ni = 0; ni < 2; ++ni) {
      const int col = n0 + wn * 32 + ni * 16 + fr;
      const float bsv = bias[col];
#pragma unroll
      for (int r = 0; r < 4; ++r) {
        const int row = m0 + wm * 64 + mi * 16 + g * 4 + r;
        out[(size_t)row * DIMD + col] = acc[mi][ni][r] + bsv;
      }
    }
}

// ---------------------------------------------------------------------------
// f16 MFMA flash attention, swapped-QK^T / in-register-P, QBLK=64, permuted-V
// (single ds_read_b128 PV A-frags).  Unchanged from round 12.
// ---------------------------------------------------------------------------
__global__ __launch_bounds__(256) void flash_kernel(
    const _Float16* __restrict__ qh, const _Float16* __restrict__ kh,
    const _Float16* __restrict__ vt, const _Float16* __restrict__ sg,
    _Float16* __restrict__ ag) {
  __shared__ _Float16 K_lds[4096];
  __shared__ _Float16 Vt_lds[4096];
  const int t = threadIdx.x;
  const int lane = t & 63;
  const int w = t >> 6;
  const int fr = lane & 15;
  const int g = lane >> 4;
  const int flat = blockIdx.x;                    // 1024 blocks
  const int swz = (flat & 7) * 128 + (flat >> 3); // 4 bh x 32 q-tiles per XCD
  const int bh = swz >> 5;
  const int q0 = (swz & 31) * 64;
  const size_t kvbase = (size_t)bh * (SEQ * HDIM);

  h8 qb[2];
  {
    const _Float16* qp = qh + kvbase + (size_t)(q0 + 16 * w + fr) * HDIM + 8 * g;
    qb[0] = *(const h8*)(qp);
    qb[1] = *(const h8*)(qp + 32);
  }

  f32x4 oacc[4];
  float m_i = -1e30f, l_i = 0.f;
#pragma unroll
  for (int df = 0; df < 4; ++df) oacc[df] = (f32x4){0.f, 0.f, 0.f, 0.f};

  const int srow = t >> 2;       // 0..63
  const int scb = (t & 3) * 16;  // 0,16,32,48
  const int vbase = ((scb >> 4) >> 1) * 32 + ((scb >> 4) & 1) * 4;
  const _Float16* kp = kh + kvbase;
  const _Float16* vp = vt + kvbase + (size_t)srow * SEQ;

  h8 k0v = *(const h8*)(kp + (size_t)srow * HDIM + scb);
  h8 k1v = *(const h8*)(kp + (size_t)srow * HDIM + scb + 8);
  h8 v0v = *(const h8*)(vp + scb);
  h8 v1v = *(const h8*)(vp + scb + 8);

  for (int j0 = 0; j0 < SEQ; j0 += 64) {
    __syncthreads();
    *(h8*)&K_lds[SWE(srow, scb)] = k0v;
    *(h8*)&K_lds[SWE(srow, scb + 8)] = k1v;
    {
      h4 a0 = __builtin_shufflevector(v0v, v0v, 0, 1, 2, 3);
      h4 a1 = __builtin_shufflevector(v0v, v0v, 4, 5, 6, 7);
      h4 b0 = __builtin_shufflevector(v1v, v1v, 0, 1, 2, 3);
      h4 b1 = __builtin_shufflevector(v1v, v1v, 4, 5, 6, 7);
      *(h4*)&Vt_lds[SWE(srow, vbase)] = a0;
      *(h4*)&Vt_lds[SWE(srow, vbase + 8)] = a1;
      *(h4*)&Vt_lds[SWE(srow, vbase + 16)] = b0;
      *(h4*)&Vt_lds[SWE(srow, vbase + 24)] = b1;
    }
    if (j0 + 64 < SEQ) {
      k0v = *(const h8*)(kp + (size_t)(j0 + 64 + srow) * HDIM + scb);
      k1v = *(const h8*)(kp + (size_t)(j0 + 64 + srow) * HDIM + scb + 8);
      v0v = *(const h8*)(vp + j0 + 64 + scb);
      v1v = *(const h8*)(vp + j0 + 64 + scb + 8);
    }
    __syncthreads();

    f32x4 sacc[4];
#pragma unroll
    for (int nf = 0; nf < 4; ++nf) sacc[nf] = (f32x4){0.f, 0.f, 0.f, 0.f};

    __builtin_amdgcn_s_setprio(1);
#pragma unroll
    for (int nf = 0; nf < 4; ++nf) {
      h8 ka0 = *(const h8*)&K_lds[SWE(16 * nf + fr, 8 * g)];
      h8 ka1 = *(const h8*)&K_lds[SWE(16 * nf + fr, 32 + 8 * g)];
      sacc[nf] =
          __builtin_amdgcn_mfma_f32_16x16x32_f16(ka0, qb[0], sacc[nf], 0, 0, 0);
      sacc[nf] =
          __builtin_amdgcn_mfma_f32_16x16x32_f16(ka1, qb[1], sacc[nf], 0, 0, 0);
    }
    __builtin_amdgcn_s_setprio(0);

    float m0 = fmaxf(fmaxf(sacc[0][0], sacc[0][1]), sacc[0][2]);
    float m1 = fmaxf(fmaxf(sacc[0][3], sacc[1][0]), sacc[1][1]);
    float m2 = fmaxf(fmaxf(sacc[1][2], sacc[1][3]), sacc[2][0]);
    float m3 = fmaxf(fmaxf(sacc[2][1], sacc[2][2]), sacc[2][3]);
    float m4 = fmaxf(fmaxf(sacc[3][0], sacc[3][1]), sacc[3][2]);
    float mx =
        fmaxf(fmaxf(fmaxf(fmaxf(m0, m1), m2), fmaxf(m3, m4)), sacc[3][3]);
    mx = fmaxf(mx, __shfl_xor(mx, 16));
    mx = fmaxf(mx, __shfl_xor(mx, 32));
    const int allskip = __all(mx <= m_i + 8.0f);
    const float mn = allskip ? m_i : fmaxf(m_i, mx);
    float p[4][4];
    float rs = 0.f;
#pragma unroll
    for (int nf = 0; nf < 4; ++nf)
#pragma unroll
      for (int r = 0; r < 4; ++r) {
        p[nf][r] = __expf(sacc[nf][r] - mn);
        rs += p[nf][r];
      }
    rs += __shfl_xor(rs, 16);
    rs += __shfl_xor(rs, 32);
    if (allskip) {
      l_i += rs;
    } else {
      float f = __expf(m_i - mn);
      l_i = l_i * f + rs;
      m_i = mn;
      f32x4 fv = (f32x4){f, f, f, f};
#pragma unroll
      for (int df = 0; df < 4; ++df) oacc[df] *= fv;
    }
    h8 pb[2];
#pragma unroll
    for (int m2i = 0; m2i < 2; ++m2i) {
      union {
        h8 v;
        fp16x2 h[4];
      } u;
      u.h[0] = __builtin_amdgcn_cvt_pkrtz(p[2 * m2i][0], p[2 * m2i][1]);
      u.h[1] = __builtin_amdgcn_cvt_pkrtz(p[2 * m2i][2], p[2 * m2i][3]);
      u.h[2] = __builtin_amdgcn_cvt_pkrtz(p[2 * m2i + 1][0], p[2 * m2i + 1][1]);
      u.h[3] = __builtin_amdgcn_cvt_pkrtz(p[2 * m2i + 1][2], p[2 * m2i + 1][3]);
      pb[m2i] = u.v;
    }

    __builtin_amdgcn_s_setprio(1);
#pragma unroll
    for (int df = 0; df < 4; ++df) {
#pragma unroll
      for (int m2i = 0; m2i < 2; ++m2i) {
        h8 va = *(const h8*)&Vt_lds[SWE(16 * df + fr, m2i * 32 + 8 * g)];
        oacc[df] =
            __builtin_amdgcn_mfma_f32_16x16x32_f16(va, pb[m2i], oacc[df], 0, 0, 0);
      }
    }
    __builtin_amdgcn_s_setprio(0);
  }

  const int b = bh >> 4, h = bh & 15;
  const int qrow = q0 + 16 * w + fr;
  const float inv = 1.0f / l_i;
  const size_t obase = ((size_t)(b * SEQ + qrow)) * DIMD + h * HDIM;
#pragma unroll
  for (int df = 0; df < 4; ++df) {
    const int d0 = 16 * df + 4 * g;
    h4 gt = *(const h4*)&sg[obase + d0];
    h4 ov;
#pragma unroll
    for (int r = 0; r < 4; ++r)
      ov[r] = (_Float16)(oacc[df][r] * inv * (float)gt[r]);
    *(h4*)&ag[obase + d0] = ov;
  }
}

// ---------------------------------------------------------------------------
extern "C" void kernel_launch(void* const* d_in, const int* in_sizes, int n_in,
                              void* d_out, int out_size, void* d_ws,
                              size_t ws_size, hipStream_t stream) {
  const float* query = (const float*)d_in[0];
  const float* Wq = (const float*)d_in[1];
  const float* bq = (const float*)d_in[2];
  const float* Wk = (const float*)d_in[3];
  const float* bk = (const float*)d_in[4];
  const float* Wv = (const float*)d_in[5];
  const float* bv = (const float*)d_in[6];
  const float* Wo = (const float*)d_in[7];
  const float* bo = (const float*)d_in[8];
  float* out = (float*)d_out;

  float* fws = (float*)d_ws;
  float* sintab = fws;
  float* costab = fws + 65536;
  _Float16* Ah = (_Float16*)(fws + 131072);  // query f16 / later ag
  _Float16* Wqh = Ah + 4194304;
  _Float16* Wkh = Wqh + 2097152;
  _Float16* Wvh = Wkh + 1048576;
  _Float16* Woh = Wvh + 1048576;
  _Float16* qw = Woh + 1048576;   // (B,H,S,64) q, roped, pre-scaled
  _Float16* kw = qw + 4194304;    // (B,H,S,64) k, roped
  _Float16* vtw = kw + 4194304;   // (B,H,64,S) v transposed
  _Float16* sg = vtw + 4194304;   // (B,S,D) sigmoid(gate)
  _Float16* ag = Ah;              // reuse after qkv gemm

  prep_kernel<<<9280, 256, 0, stream>>>(query, Wq, Wk, Wv, Wo, Ah, Wqh, Wkh,
                                        Wvh, Woh, sintab, costab);

  qkv_kernel<<<dim3(16, 16), 512, 0, stream>>>(Ah, Wqh, Wkh, Wvh, bq, bk, bv,
                                               qw, sg, kw, vtw, sintab, costab);

  flash_kernel<<<1024, 256, 0, stream>>>(qw, kw, vtw, sg, ag);

  ogemm_kernel<<<dim3(16, 32), 256, 0, stream>>>(ag, Woh, bo, out);
}

// Round 14
// 156.642 us; speedup vs baseline: 1.1294x; 1.1294x over previous
//
#include <hip/hip_runtime.h>
#include <math.h>

#define SEQ 2048
#define DIMD 1024
#define NH 16
#define HDIM 64

typedef _Float16 h8 __attribute__((ext_vector_type(8)));
typedef _Float16 h4 __attribute__((ext_vector_type(4)));
typedef __fp16 fp16x2 __attribute__((ext_vector_type(2)));
typedef float f32x4 __attribute__((ext_vector_type(4)));

typedef const __attribute__((address_space(1))) void* gas_t;
typedef __attribute__((address_space(3))) void* las_t;

// element-index swizzle for [*][64] f16 tiles (128B rows): XOR element bits
// 3-5 with (row&7).  Permutes 16B chunks within a row.
__device__ __forceinline__ int SWE(int r, int c) {
  return ((r << 6) + c) ^ ((r & 7) << 3);
}

// ---------------------------------------------------------------------------
// Fused prep: RoPE table (double precision) + f32->f16 converts.
// ---------------------------------------------------------------------------
#define R0 16384           // rope items (x4 idx each)
#define R1 (R0 + 1048576)  // query f32x4
#define R2 (R1 + 524288)   // Wq
#define R3 (R2 + 262144)   // Wk
#define R4 (R3 + 262144)   // Wv
#define R5 (R4 + 262144)   // Wo

__global__ void prep_kernel(const float* __restrict__ query,
                            const float* __restrict__ Wq,
                            const float* __restrict__ Wk,
                            const float* __restrict__ Wv,
                            const float* __restrict__ Wo,
                            _Float16* __restrict__ Ah,
                            _Float16* __restrict__ Wqh,
                            _Float16* __restrict__ Wkh,
                            _Float16* __restrict__ Wvh,
                            _Float16* __restrict__ Woh,
                            float* __restrict__ sintab,
                            float* __restrict__ costab) {
  int i = blockIdx.x * 256 + threadIdx.x;
  if (i < R0) {
#pragma unroll
    for (int j = 0; j < 4; ++j) {
      int idx = i * 4 + j;
      int tp = idx >> 5;
      int fi = idx & 31;
      double inv = pow(10000.0, -(double)(2 * fi) / 64.0);
      double a = (double)tp * inv;
      sintab[idx] = (float)sin(a);
      costab[idx] = (float)cos(a);
    }
    return;
  }
  const float* src;
  _Float16* dst;
  int k;
  if (i < R1) {
    k = i - R0; src = query; dst = Ah;
  } else if (i < R2) {
    k = i - R1; src = Wq; dst = Wqh;
  } else if (i < R3) {
    k = i - R2; src = Wk; dst = Wkh;
  } else if (i < R4) {
    k = i - R3; src = Wv; dst = Wvh;
  } else if (i < R5) {
    k = i - R4; src = Wo; dst = Woh;
  } else {
    return;
  }
  float4 v = ((const float4*)src)[k];
  h4 H;
  H[0] = (_Float16)v.x;
  H[1] = (_Float16)v.y;
  H[2] = (_Float16)v.z;
  H[3] = (_Float16)v.w;
  ((h4*)dst)[k] = H;
}

// ---------------------------------------------------------------------------
// Fused QKV projection GEMM, concat N=4096.  Tile 128x128, BK=64, dbuf LDS
// staged via global_load_lds with pre-swizzled per-lane source (SWE layout),
// counted vmcnt pipeline (never 0 mid-loop), raw s_barrier.  4 waves of
// 64x64.  Grid flat 1024, XCD-chunked swizzle.  (r8 best-known: 71.7 us)
// ---------------------------------------------------------------------------
__global__ __launch_bounds__(256) void qkv_kernel(
    const _Float16* __restrict__ Ah, const _Float16* __restrict__ Wqh,
    const _Float16* __restrict__ Wkh, const _Float16* __restrict__ Wvh,
    const float* __restrict__ bq, const float* __restrict__ bk,
    const float* __restrict__ bv, _Float16* __restrict__ qw,
    _Float16* __restrict__ sg, _Float16* __restrict__ kw,
    _Float16* __restrict__ vtw, const float* __restrict__ sintab,
    const float* __restrict__ costab) {
  __shared__ _Float16 Abuf[2][8192];
  __shared__ _Float16 Bbuf[2][8192];
  const int t = threadIdx.x;
  const int lane = t & 63;
  const int w = t >> 6;
  const int wm = w & 1, wn = w >> 1;
  const int fr = lane & 15;
  const int g = lane >> 4;
  const int flat = blockIdx.x;                    // 1024 blocks
  const int swz = (flat & 7) * 128 + (flat >> 3); // XCD-contiguous chunks
  const int m0 = (swz >> 5) * 128;
  const int n0 = (swz & 31) * 128;
  const int region = (n0 < 2048) ? 0 : (n0 < 3072 ? 1 : 2);
  const _Float16* Wb = region == 0   ? Wqh + (size_t)n0 * DIMD
                       : region == 1 ? Wkh + (size_t)(n0 - 2048) * DIMD
                                     : Wvh + (size_t)(n0 - 3072) * DIMD;
  const float* bias = region == 0   ? bq + n0
                      : region == 1 ? bk + (n0 - 2048)
                                    : bv + (n0 - 3072);

  f32x4 acc[4][4];
#pragma unroll
  for (int i = 0; i < 4; ++i)
#pragma unroll
    for (int j = 0; j < 4; ++j) acc[i][j] = (f32x4){0.f, 0.f, 0.f, 0.f};

  // staging source: lane L reads 16B of row (base + L>>3), chunk (L&7)^(L>>3)
  const int rsub = lane >> 3;
  const int csw = ((lane & 7) ^ rsub) << 3;
  const _Float16* gA = Ah + (size_t)(m0 + w * 32 + rsub) * DIMD + csw;
  const _Float16* gB = Wb + (size_t)(w * 32 + rsub) * DIMD + csw;
  const int ldsb = w * 2048;

  auto stage = [&](int kt, int pb) {
#pragma unroll
    for (int i = 0; i < 4; ++i) {
      __builtin_amdgcn_global_load_lds(
          (gas_t)(gA + (size_t)i * 8 * DIMD + kt * 64),
          (las_t)&Abuf[pb][ldsb + i * 512], 16, 0, 0);
      __builtin_amdgcn_global_load_lds(
          (gas_t)(gB + (size_t)i * 8 * DIMD + kt * 64),
          (las_t)&Bbuf[pb][ldsb + i * 512], 16, 0, 0);
    }
  };

  stage(0, 0);
  for (int kt = 0; kt < 16; ++kt) {
    const int pb = kt & 1;
    if (kt < 15) {
      stage(kt + 1, pb ^ 1);
      asm volatile("s_waitcnt vmcnt(8)" ::: "memory");
    } else {
      asm volatile("s_waitcnt vmcnt(0)" ::: "memory");
    }
    __builtin_amdgcn_sched_barrier(0);
    __builtin_amdgcn_s_barrier();
#pragma unroll
    for (int s = 0; s < 2; ++s) {
      h8 av[4], bv[4];
#pragma unroll
      for (int mi = 0; mi < 4; ++mi)
        av[mi] = *(const h8*)&Abuf[pb][SWE(wm * 64 + mi * 16 + fr, 8 * g + 32 * s)];
#pragma unroll
      for (int ni = 0; ni < 4; ++ni)
        bv[ni] = *(const h8*)&Bbuf[pb][SWE(wn * 64 + ni * 16 + fr, 8 * g + 32 * s)];
      __builtin_amdgcn_s_setprio(1);
#pragma unroll
      for (int mi = 0; mi < 4; ++mi)
#pragma unroll
        for (int ni = 0; ni < 4; ++ni)
          acc[mi][ni] = __builtin_amdgcn_mfma_f32_16x16x32_f16(
              av[mi], bv[ni], acc[mi][ni], 0, 0, 0);
      __builtin_amdgcn_s_setprio(0);
    }
    __builtin_amdgcn_s_barrier();
  }

  // Epilogue. C/D layout: col = lane&15, row = (lane>>4)*4 + reg.
#pragma unroll
  for (int mi = 0; mi < 4; ++mi)
#pragma unroll
    for (int ni = 0; ni < 4; ++ni) {
      const int cl = wn * 64 + ni * 16 + fr;
      const float bsv = bias[cl];
      if (region == 2) {  // V: vectorized h4 store (4 consecutive s)
        const int vc = (n0 - 3072) + cl;
        const int h = vc >> 6, d = vc & 63;
        const int row0 = m0 + wm * 64 + mi * 16 + g * 4;
        const int b = row0 >> 11;
        const int s0 = row0 & (SEQ - 1);
        h4 vv;
#pragma unroll
        for (int r = 0; r < 4; ++r) vv[r] = (_Float16)(acc[mi][ni][r] + bsv);
        *(h4*)&vtw[((size_t)(b * NH + h) * HDIM + d) * SEQ + s0] = vv;
        continue;
      }
#pragma unroll
      for (int r = 0; r < 4; ++r) {
        const int row = m0 + wm * 64 + mi * 16 + g * 4 + r;
        float v = acc[mi][ni][r] + bsv;
        const int b = row >> 11;
        const int s = row & (SEQ - 1);
        if (region == 0) {
          const int h = n0 >> 7;
          const int d = cl & 63;
          if (wn == 0) {  // q: rope + SCALE
            float vp = __shfl_xor(v, 1);
            const int pi = s * 32 + (d >> 1);
            float sn = sintab[pi], cs = costab[pi];
            float rv = (d & 1) ? (vp * sn + v * cs) : (v * cs - vp * sn);
            rv *= 0.125f;
            qw[((size_t)(b * NH + h) * SEQ + s) * HDIM + d] = (_Float16)rv;
          } else {  // gate: sigmoid -> (B,S,D)
            float gv = 1.0f / (1.0f + __expf(-v));
            sg[((size_t)(b * SEQ + s)) * DIMD + h * HDIM + d] = (_Float16)gv;
          }
        } else {  // region 1: K rope
          const int kc = (n0 - 2048) + cl;
          const int h = kc >> 6, d = kc & 63;
          float vp = __shfl_xor(v, 1);
          const int pi = s * 32 + (d >> 1);
          float sn = sintab[pi], cs = costab[pi];
          float rv = (d & 1) ? (vp * sn + v * cs) : (v * cs - vp * sn);
          kw[((size_t)(b * NH + h) * SEQ + s) * HDIM + d] = (_Float16)rv;
        }
      }
    }
}

// ---------------------------------------------------------------------------
// O-projection GEMM (plain f16): BM=128, BN=64, BK=64, dbuf gload_lds
// pipeline with counted vmcnt(6).  4 waves (2x2) of 64x32.  Grid flat 512,
// XCD swizzle.  (r8 config)
// ---------------------------------------------------------------------------
__global__ __launch_bounds__(256) void ogemm_kernel(
    const _Float16* __restrict__ ag, const _Float16* __restrict__ Woh,
    const float* __restrict__ bias, float* __restrict__ out) {
  __shared__ _Float16 Abuf[2][8192];
  __shared__ _Float16 Bbuf[2][4096];
  const int t = threadIdx.x;
  const int lane = t & 63;
  const int w = t >> 6;
  const int wm = w & 1, wn = w >> 1;
  const int fr = lane & 15;
  const int g = lane >> 4;
  const int flat = blockIdx.x;                   // 512 blocks
  const int swz = (flat & 7) * 64 + (flat >> 3);
  const int m0 = (swz >> 4) * 128;
  const int n0 = (swz & 15) * 64;

  f32x4 acc[4][2];
#pragma unroll
  for (int i = 0; i < 4; ++i)
#pragma unroll
    for (int j = 0; j < 2; ++j) acc[i][j] = (f32x4){0.f, 0.f, 0.f, 0.f};

  const int rsub = lane >> 3;
  const int csw = ((lane & 7) ^ rsub) << 3;
  const _Float16* gA = ag + (size_t)(m0 + w * 32 + rsub) * DIMD + csw;
  const _Float16* gB = Woh + (size_t)(n0 + w * 16 + rsub) * DIMD + csw;
  const int ldsbA = w * 2048;
  const int ldsbB = w * 1024;

  auto stage = [&](int kt, int pb) {
#pragma unroll
    for (int i = 0; i < 4; ++i)
      __builtin_amdgcn_global_load_lds(
          (gas_t)(gA + (size_t)i * 8 * DIMD + kt * 64),
          (las_t)&Abuf[pb][ldsbA + i * 512], 16, 0, 0);
#pragma unroll
    for (int i = 0; i < 2; ++i)
      __builtin_amdgcn_global_load_lds(
          (gas_t)(gB + (size_t)i * 8 * DIMD + kt * 64),
          (las_t)&Bbuf[pb][ldsbB + i * 512], 16, 0, 0);
  };

  stage(0, 0);
  for (int kt = 0; kt < 16; ++kt) {
    const int pb = kt & 1;
    if (kt < 15) {
      stage(kt + 1, pb ^ 1);
      asm volatile("s_waitcnt vmcnt(6)" ::: "memory");
    } else {
      asm volatile("s_waitcnt vmcnt(0)" ::: "memory");
    }
    __builtin_amdgcn_sched_barrier(0);
    __builtin_amdgcn_s_barrier();
#pragma unroll
    for (int s = 0; s < 2; ++s) {
      h8 av[4], bv[2];
#pragma unroll
      for (int mi = 0; mi < 4; ++mi)
        av[mi] = *(const h8*)&Abuf[pb][SWE(wm * 64 + mi * 16 + fr, 8 * g + 32 * s)];
#pragma unroll
      for (int ni = 0; ni < 2; ++ni)
        bv[ni] = *(const h8*)&Bbuf[pb][SWE(wn * 32 + ni * 16 + fr, 8 * g + 32 * s)];
      __builtin_amdgcn_s_setprio(1);
#pragma unroll
      for (int mi = 0; mi < 4; ++mi)
#pragma unroll
        for (int ni = 0; ni < 2; ++ni)
          acc[mi][ni] = __builtin_amdgcn_mfma_f32_16x16x32_f16(
              av[mi], bv[ni], acc[mi][ni], 0, 0, 0);
      __builtin_amdgcn_s_setprio(0);
    }
    __builtin_amdgcn_s_barrier();
  }

#pragma unroll
  for (int mi = 0; mi < 4; ++mi)
#pragma unroll
    for (int ni = 0; ni < 2; ++ni) {
      const int col = n0 + wn * 32 + ni * 16 + fr;
      const float bsv = bias[col];
#pragma unroll
      for (int r = 0; r < 4; ++r) {
        const int row = m0 + wm * 64 + mi * 16 + g * 4 + r;
        out[(size_t)row * DIMD + col] = acc[mi][ni][r] + bsv;
      }
    }
}

// ---------------------------------------------------------------------------
// f16 MFMA flash attention, swapped-QK^T / in-register-P, QBLK=64, permuted-V
// (single ds_read_b128 PV A-frags).  (r12 config)
// ---------------------------------------------------------------------------
__global__ __launch_bounds__(256) void flash_kernel(
    const _Float16* __restrict__ qh, const _Float16* __restrict__ kh,
    const _Float16* __restrict__ vt, const _Float16* __restrict__ sg,
    _Float16* __restrict__ ag) {
  __shared__ _Float16 K_lds[4096];
  __shared__ _Float16 Vt_lds[4096];
  const int t = threadIdx.x;
  const int lane = t & 63;
  const int w = t >> 6;
  const int fr = lane & 15;
  const int g = lane >> 4;
  const int flat = blockIdx.x;                    // 1024 blocks
  const int swz = (flat & 7) * 128 + (flat >> 3); // 4 bh x 32 q-tiles per XCD
  const int bh = swz >> 5;
  const int q0 = (swz & 31) * 64;
  const size_t kvbase = (size_t)bh * (SEQ * HDIM);

  h8 qb[2];
  {
    const _Float16* qp = qh + kvbase + (size_t)(q0 + 16 * w + fr) * HDIM + 8 * g;
    qb[0] = *(const h8*)(qp);
    qb[1] = *(const h8*)(qp + 32);
  }

  f32x4 oacc[4];
  float m_i = -1e30f, l_i = 0.f;
#pragma unroll
  for (int df = 0; df < 4; ++df) oacc[df] = (f32x4){0.f, 0.f, 0.f, 0.f};

  const int srow = t >> 2;       // 0..63
  const int scb = (t & 3) * 16;  // 0,16,32,48
  const int vbase = ((scb >> 4) >> 1) * 32 + ((scb >> 4) & 1) * 4;
  const _Float16* kp = kh + kvbase;
  const _Float16* vp = vt + kvbase + (size_t)srow * SEQ;

  h8 k0v = *(const h8*)(kp + (size_t)srow * HDIM + scb);
  h8 k1v = *(const h8*)(kp + (size_t)srow * HDIM + scb + 8);
  h8 v0v = *(const h8*)(vp + scb);
  h8 v1v = *(const h8*)(vp + scb + 8);

  for (int j0 = 0; j0 < SEQ; j0 += 64) {
    __syncthreads();
    *(h8*)&K_lds[SWE(srow, scb)] = k0v;
    *(h8*)&K_lds[SWE(srow, scb + 8)] = k1v;
    {
      h4 a0 = __builtin_shufflevector(v0v, v0v, 0, 1, 2, 3);
      h4 a1 = __builtin_shufflevector(v0v, v0v, 4, 5, 6, 7);
      h4 b0 = __builtin_shufflevector(v1v, v1v, 0, 1, 2, 3);
      h4 b1 = __builtin_shufflevector(v1v, v1v, 4, 5, 6, 7);
      *(h4*)&Vt_lds[SWE(srow, vbase)] = a0;
      *(h4*)&Vt_lds[SWE(srow, vbase + 8)] = a1;
      *(h4*)&Vt_lds[SWE(srow, vbase + 16)] = b0;
      *(h4*)&Vt_lds[SWE(srow, vbase + 24)] = b1;
    }
    if (j0 + 64 < SEQ) {
      k0v = *(const h8*)(kp + (size_t)(j0 + 64 + srow) * HDIM + scb);
      k1v = *(const h8*)(kp + (size_t)(j0 + 64 + srow) * HDIM + scb + 8);
      v0v = *(const h8*)(vp + j0 + 64 + scb);
      v1v = *(const h8*)(vp + j0 + 64 + scb + 8);
    }
    __syncthreads();

    f32x4 sacc[4];
#pragma unroll
    for (int nf = 0; nf < 4; ++nf) sacc[nf] = (f32x4){0.f, 0.f, 0.f, 0.f};

    __builtin_amdgcn_s_setprio(1);
#pragma unroll
    for (int nf = 0; nf < 4; ++nf) {
      h8 ka0 = *(const h8*)&K_lds[SWE(16 * nf + fr, 8 * g)];
      h8 ka1 = *(const h8*)&K_lds[SWE(16 * nf + fr, 32 + 8 * g)];
      sacc[nf] =
          __builtin_amdgcn_mfma_f32_16x16x32_f16(ka0, qb[0], sacc[nf], 0, 0, 0);
      sacc[nf] =
          __builtin_amdgcn_mfma_f32_16x16x32_f16(ka1, qb[1], sacc[nf], 0, 0, 0);
    }
    __builtin_amdgcn_s_setprio(0);

    float m0 = fmaxf(fmaxf(sacc[0][0], sacc[0][1]), sacc[0][2]);
    float m1 = fmaxf(fmaxf(sacc[0][3], sacc[1][0]), sacc[1][1]);
    float m2 = fmaxf(fmaxf(sacc[1][2], sacc[1][3]), sacc[2][0]);
    float m3 = fmaxf(fmaxf(sacc[2][1], sacc[2][2]), sacc[2][3]);
    float m4 = fmaxf(fmaxf(sacc[3][0], sacc[3][1]), sacc[3][2]);
    float mx =
        fmaxf(fmaxf(fmaxf(fmaxf(m0, m1), m2), fmaxf(m3, m4)), sacc[3][3]);
    mx = fmaxf(mx, __shfl_xor(mx, 16));
    mx = fmaxf(mx, __shfl_xor(mx, 32));
    const int allskip = __all(mx <= m_i + 8.0f);
    const float mn = allskip ? m_i : fmaxf(m_i, mx);
    float p[4][4];
    float rs = 0.f;
#pragma unroll
    for (int nf = 0; nf < 4; ++nf)
#pragma unroll
      for (int r = 0; r < 4; ++r) {
        p[nf][r] = __expf(sacc[nf][r] - mn);
        rs += p[nf][r];
      }
    rs += __shfl_xor(rs, 16);
    rs += __shfl_xor(rs, 32);
    if (allskip) {
      l_i += rs;
    } else {
      float f = __expf(m_i - mn);
      l_i = l_i * f + rs;
      m_i = mn;
      f32x4 fv = (f32x4){f, f, f, f};
#pragma unroll
      for (int df = 0; df < 4; ++df) oacc[df] *= fv;
    }
    h8 pb[2];
#pragma unroll
    for (int m2i = 0; m2i < 2; ++m2i) {
      union {
        h8 v;
        fp16x2 h[4];
      } u;
      u.h[0] = __builtin_amdgcn_cvt_pkrtz(p[2 * m2i][0], p[2 * m2i][1]);
      u.h[1] = __builtin_amdgcn_cvt_pkrtz(p[2 * m2i][2], p[2 * m2i][3]);
      u.h[2] = __builtin_amdgcn_cvt_pkrtz(p[2 * m2i + 1][0], p[2 * m2i + 1][1]);
      u.h[3] = __builtin_amdgcn_cvt_pkrtz(p[2 * m2i + 1][2], p[2 * m2i + 1][3]);
      pb[m2i] = u.v;
    }

    __builtin_amdgcn_s_setprio(1);
#pragma unroll
    for (int df = 0; df < 4; ++df) {
#pragma unroll
      for (int m2i = 0; m2i < 2; ++m2i) {
        h8 va = *(const h8*)&Vt_lds[SWE(16 * df + fr, m2i * 32 + 8 * g)];
        oacc[df] =
            __builtin_amdgcn_mfma_f32_16x16x32_f16(va, pb[m2i], oacc[df], 0, 0, 0);
      }
    }
    __builtin_amdgcn_s_setprio(0);
  }

  const int b = bh >> 4, h = bh & 15;
  const int qrow = q0 + 16 * w + fr;
  const float inv = 1.0f / l_i;
  const size_t obase = ((size_t)(b * SEQ + qrow)) * DIMD + h * HDIM;
#pragma unroll
  for (int df = 0; df < 4; ++df) {
    const int d0 = 16 * df + 4 * g;
    h4 gt = *(const h4*)&sg[obase + d0];
    h4 ov;
#pragma unroll
    for (int r = 0; r < 4; ++r)
      ov[r] = (_Float16)(oacc[df][r] * inv * (float)gt[r]);
    *(h4*)&ag[obase + d0] = ov;
  }
}

// ---------------------------------------------------------------------------
extern "C" void kernel_launch(void* const* d_in, const int* in_sizes, int n_in,
                              void* d_out, int out_size, void* d_ws,
                              size_t ws_size, hipStream_t stream) {
  const float* query = (const float*)d_in[0];
  const float* Wq = (const float*)d_in[1];
  const float* bq = (const float*)d_in[2];
  const float* Wk = (const float*)d_in[3];
  const float* bk = (const float*)d_in[4];
  const float* Wv = (const float*)d_in[5];
  const float* bv = (const float*)d_in[6];
  const float* Wo = (const float*)d_in[7];
  const float* bo = (const float*)d_in[8];
  float* out = (float*)d_out;

  float* fws = (float*)d_ws;
  float* sintab = fws;
  float* costab = fws + 65536;
  _Float16* Ah = (_Float16*)(fws + 131072);  // query f16 / later ag
  _Float16* Wqh = Ah + 4194304;
  _Float16* Wkh = Wqh + 2097152;
  _Float16* Wvh = Wkh + 1048576;
  _Float16* Woh = Wvh + 1048576;
  _Float16* qw = Woh + 1048576;   // (B,H,S,64) q, roped, pre-scaled
  _Float16* kw = qw + 4194304;    // (B,H,S,64) k, roped
  _Float16* vtw = kw + 4194304;   // (B,H,64,S) v transposed
  _Float16* sg = vtw + 4194304;   // (B,S,D) sigmoid(gate)
  _Float16* ag = Ah;              // reuse after qkv gemm

  prep_kernel<<<9280, 256, 0, stream>>>(query, Wq, Wk, Wv, Wo, Ah, Wqh, Wkh,
                                        Wvh, Woh, sintab, costab);

  qkv_kernel<<<1024, 256, 0, stream>>>(Ah, Wqh, Wkh, Wvh, bq, bk, bv, qw, sg,
                                       kw, vtw, sintab, costab);

  flash_kernel<<<1024, 256, 0, stream>>>(qw, kw, vtw, sg, ag);

  ogemm_kernel<<<512, 256, 0, stream>>>(ag, Woh, bo, out);
}